// Round 4
// baseline (446.828 us; speedup 1.0000x reference)
//
#include <hip/hip_runtime.h>
#include <stdint.h>

// Problem constants
#define B_    4
#define CQ_   256
#define CKV_  256
#define NQ_   2048
#define NKV_  2048
#define H_    8
#define DK_   64
#define HD_   512   // H_*DK_

typedef __attribute__((ext_vector_type(8))) short bf16x8;
typedef __attribute__((ext_vector_type(4))) float f32x4;

__device__ __forceinline__ short f2bf(float f) {
    unsigned u = __builtin_bit_cast(unsigned, f);
    u = (u + 0x7FFFu + ((u >> 16) & 1u)) >> 16;   // RNE truncate to bf16
    return (short)u;
}

#define MFMA16(a, b, c) __builtin_amdgcn_mfma_f32_16x16x32_bf16((a), (b), (c), 0, 0, 0)

// ---------------------------------------------------------------------------
// Two-level device-scope barrier, contention-managed (round-3 post-mortem:
// flat 512-way same-line atomicAdd + poll storm = ~57us/barrier hot-spot).
//   level 0: 16 groups x 32 blocks, per-group arrival counter on its OWN
//            128B line  -> <=32 same-line RMWs per phase
//   level 1: 16 group-leaders on one top counter (16 RMWs, 16 pollers)
//   release: leader writes per-group release word; 31 peers poll their
//            own line (single write, read-mostly)
// Monotone targets (phase index), never reset; zeroed once per launch.
// ---------------------------------------------------------------------------
#define NGRP_   16
#define GRPSZ_  32   // 512 blocks / 16 groups

__device__ __forceinline__ void gbar(unsigned* grpCnt, unsigned* top,
                                     unsigned* grpRel, int g, int phase) {
    __syncthreads();
    if (threadIdx.x == 0) {
        __threadfence();   // release this block's phase writes
        const unsigned old = __hip_atomic_fetch_add(
            &grpCnt[g * 32], 1u, __ATOMIC_ACQ_REL, __HIP_MEMORY_SCOPE_AGENT);
        if (old == (unsigned)(GRPSZ_ * phase - 1)) {
            // last arriver of this group
            __hip_atomic_fetch_add(top, 1u, __ATOMIC_ACQ_REL,
                                   __HIP_MEMORY_SCOPE_AGENT);
            while (__hip_atomic_load(top, __ATOMIC_ACQUIRE,
                                     __HIP_MEMORY_SCOPE_AGENT)
                   < (unsigned)(NGRP_ * phase))
                __builtin_amdgcn_s_sleep(4);
            __hip_atomic_store(&grpRel[g * 32], (unsigned)phase,
                               __ATOMIC_RELEASE, __HIP_MEMORY_SCOPE_AGENT);
        } else {
            while (__hip_atomic_load(&grpRel[g * 32], __ATOMIC_ACQUIRE,
                                     __HIP_MEMORY_SCOPE_AGENT)
                   < (unsigned)phase)
                __builtin_amdgcn_s_sleep(8);
        }
        __threadfence();   // acquire: invalidate stale caches for next phase
    }
    __syncthreads();
}

// =========================================================================
// Fused persistent kernel: 5 phases, 4 device-scope barriers, 1 dispatch.
//   grid = 512 blocks x 256 threads; __launch_bounds__(256,2) + 18.4KB LDS
//   => 2 blocks/CU co-resident on 256 CUs (proved by round-3 completion).
// Phase bodies byte-identical to round-3 passing kernel.
// =========================================================================
__global__ __launch_bounds__(256, 2) void fused_kernel(
    const float* __restrict__ x_q,
    const float* __restrict__ x_kv,
    const float* __restrict__ Wq,
    const float* __restrict__ Wk,
    const float* __restrict__ Wv,
    const float* __restrict__ Wo,
    const float* __restrict__ gamma,
    float* __restrict__ out,
    unsigned short* __restrict__ xkv_bf,
    unsigned short* __restrict__ xqt_bf,
    unsigned short* __restrict__ P,
    unsigned short* __restrict__ Qt,
    unsigned short* __restrict__ Gsum,
    unsigned short* __restrict__ Zt,
    unsigned short* __restrict__ Nbf,
    unsigned* __restrict__ grpCnt,
    unsigned* __restrict__ top,
    unsigned* __restrict__ grpRel)
{
    const int tid = threadIdx.x;
    const int bid = blockIdx.x;               // 0..511
    const int grp = bid >> 5;                 // 0..15
    const int w = tid >> 6, L = tid & 63;
    const int r16 = L & 15, q = L >> 4;

    __shared__ __align__(16) float smem[4608];   // 18.4 KB: tile[64][65] / red[4][32][36]

    // ================= Phase 0: prep + weight folds =================
    {   // 0a: x_kv f32 -> bf16, units bid*2, bid*2+1
#pragma unroll
        for (int u = 0; u < 2; ++u) {
            const size_t base = ((size_t)(bid * 2 + u) * 256 + tid) * 8;
            const f32x4 v0 = *(const f32x4*)(x_kv + base);
            const f32x4 v1 = *(const f32x4*)(x_kv + base + 4);
            bf16x8 o;
            o[0]=f2bf(v0.x); o[1]=f2bf(v0.y); o[2]=f2bf(v0.z); o[3]=f2bf(v0.w);
            o[4]=f2bf(v1.x); o[5]=f2bf(v1.y); o[6]=f2bf(v1.z); o[7]=f2bf(v1.w);
            *(bf16x8*)(xkv_bf + base) = o;
        }
    }
    {   // 0b: x_q [b][cq][n] -> xqt_bf [b][n][cq] transpose, 1 unit/blk
        const int b   = bid >> 7;
        const int t   = bid & 127;
        const int cq0 = (t & 3) * 64;
        const int n0  = (t >> 2) * 64;
        float (*tile)[65] = (float(*)[65])smem;
        const float* src = x_q + (size_t)b * CQ_ * NQ_;
        const int r_l = tid >> 4;
        const int c_l = (tid & 15) * 4;
#pragma unroll
        for (int i = 0; i < 4; ++i) {
            const int row = r_l + 16 * i;
            const f32x4 v = *(const f32x4*)(src + (size_t)(cq0 + row) * NQ_ + n0 + c_l);
            tile[row][c_l] = v.x; tile[row][c_l + 1] = v.y;
            tile[row][c_l + 2] = v.z; tile[row][c_l + 3] = v.w;
        }
        __syncthreads();
        unsigned short* dst = xqt_bf + (size_t)b * NQ_ * CQ_;
        const int cq_l = (tid & 7) * 8;
#pragma unroll
        for (int j = 0; j < 2; ++j) {
            const int n_l = (tid >> 3) + 32 * j;
            bf16x8 o;
#pragma unroll
            for (int k = 0; k < 8; ++k) o[k] = f2bf(tile[cq_l + k][n_l]);
            *(bf16x8*)(dst + (size_t)(n0 + n_l) * CQ_ + cq0 + cq_l) = o;
        }
    }
    if (bid >= 384) {   // 0c: P / Qt weight-fold GEMMs (128 units)
        const int lb0 = bid - 384;
        const bool isP = (lb0 < 64);
        const int lb = isP ? lb0 : lb0 - 64;
        const int h = lb >> 3;
        const int t = lb & 7;
        const int tm = (t >> 1) * 64;
        const int tn = (t & 1) * 128;
        const int wm = (w >> 1) * 32, wn = (w & 1) * 64;

        f32x4 acc[2][4];
#pragma unroll
        for (int mi = 0; mi < 2; ++mi)
#pragma unroll
            for (int ni = 0; ni < 4; ++ni) acc[mi][ni] = (f32x4){0.f,0.f,0.f,0.f};

#pragma unroll
        for (int kk = 0; kk < 2; ++kk) {
            const int d0 = kk * 32 + q * 8;
            bf16x8 a[2], bb[4];
            if (isP) {
#pragma unroll
                for (int mi = 0; mi < 2; ++mi) {
                    const int m = tm + wm + mi * 16 + r16;
                    const f32x4* p = (const f32x4*)(Wo + (size_t)m * HD_ + h * 64 + d0);
                    f32x4 v0 = p[0], v1 = p[1];
                    a[mi][0]=f2bf(v0.x); a[mi][1]=f2bf(v0.y); a[mi][2]=f2bf(v0.z); a[mi][3]=f2bf(v0.w);
                    a[mi][4]=f2bf(v1.x); a[mi][5]=f2bf(v1.y); a[mi][6]=f2bf(v1.z); a[mi][7]=f2bf(v1.w);
                }
#pragma unroll
                for (int ni = 0; ni < 4; ++ni) {
                    const int n = tn + wn + ni * 16 + r16;
#pragma unroll
                    for (int j = 0; j < 8; ++j)
                        bb[ni][j] = f2bf(Wv[(size_t)(h * 64 + d0 + j) * CKV_ + n]);
                }
            } else {
#pragma unroll
                for (int mi = 0; mi < 2; ++mi) {
                    const int m = tm + wm + mi * 16 + r16;
#pragma unroll
                    for (int j = 0; j < 8; ++j)
                        a[mi][j] = f2bf(Wq[(size_t)(h * 64 + d0 + j) * CQ_ + m]);
                }
#pragma unroll
                for (int ni = 0; ni < 4; ++ni) {
                    const int n = tn + wn + ni * 16 + r16;
#pragma unroll
                    for (int j = 0; j < 8; ++j)
                        bb[ni][j] = f2bf(Wk[(size_t)(h * 64 + d0 + j) * CKV_ + n]);
                }
            }
#pragma unroll
            for (int mi = 0; mi < 2; ++mi)
#pragma unroll
                for (int ni = 0; ni < 4; ++ni)
                    acc[mi][ni] = MFMA16(a[mi], bb[ni], acc[mi][ni]);
        }

#pragma unroll
        for (int mi = 0; mi < 2; ++mi)
#pragma unroll
            for (int ni = 0; ni < 4; ++ni)
#pragma unroll
                for (int r = 0; r < 4; ++r) {
                    const int m = tm + wm + mi * 16 + q * 4 + r;
                    const int n = tn + wn + ni * 16 + r16;
                    if (isP)  P [(size_t)m * 2048 + h * 256 + n] = (unsigned short)f2bf(acc[mi][ni][r]);
                    else      Qt[((size_t)h * 256 + m) * 256 + n] = (unsigned short)f2bf(acc[mi][ni][r]);
                }
    }
    gbar(grpCnt, top, grpRel, grp, 1);

    // ================= Phase 1: Gram =================
    if (bid < 256) {
        const int t = bid & 63;
        const int b = bid >> 6;
        const int tm = (t >> 3) * 32;
        const int tn = (t & 7) * 32;

        const unsigned short* Xb = xkv_bf + (size_t)b * CKV_ * NKV_;
        const unsigned short* A0 = Xb + (size_t)(tm + r16) * NKV_;
        const unsigned short* A1 = A0 + (size_t)16 * NKV_;
        const unsigned short* B0 = Xb + (size_t)(tn + r16) * NKV_;
        const unsigned short* B1 = B0 + (size_t)16 * NKV_;
        const int k0 = w * 512 + q * 8;

        f32x4 acc[2][2];
#pragma unroll
        for (int mi = 0; mi < 2; ++mi)
#pragma unroll
            for (int ni = 0; ni < 2; ++ni) acc[mi][ni] = (f32x4){0.f,0.f,0.f,0.f};

        bf16x8 aC[2], bC[2];
        aC[0] = *(const bf16x8*)(A0 + k0);
        aC[1] = *(const bf16x8*)(A1 + k0);
        bC[0] = *(const bf16x8*)(B0 + k0);
        bC[1] = *(const bf16x8*)(B1 + k0);

#pragma unroll
        for (int kk = 0; kk < 16; ++kk) {
            bf16x8 aN[2], bN[2];
            if (kk < 15) {
                const int ko = k0 + (kk + 1) * 32;
                aN[0] = *(const bf16x8*)(A0 + ko);
                aN[1] = *(const bf16x8*)(A1 + ko);
                bN[0] = *(const bf16x8*)(B0 + ko);
                bN[1] = *(const bf16x8*)(B1 + ko);
            }
            acc[0][0] = MFMA16(aC[0], bC[0], acc[0][0]);
            acc[0][1] = MFMA16(aC[0], bC[1], acc[0][1]);
            acc[1][0] = MFMA16(aC[1], bC[0], acc[1][0]);
            acc[1][1] = MFMA16(aC[1], bC[1], acc[1][1]);
            aC[0] = aN[0]; aC[1] = aN[1]; bC[0] = bN[0]; bC[1] = bN[1];
        }

        float (*red)[32][36] = (float(*)[32][36])smem;
#pragma unroll
        for (int mi = 0; mi < 2; ++mi)
#pragma unroll
            for (int ni = 0; ni < 2; ++ni)
#pragma unroll
                for (int r = 0; r < 4; ++r)
                    red[w][mi * 16 + q * 4 + r][ni * 16 + r16] = acc[mi][ni][r];
        __syncthreads();

        const int m  = tid >> 3;
        const int n4 = (tid & 7) * 4;
        f32x4 s = *(const f32x4*)&red[0][m][n4];
#pragma unroll
        for (int ww = 1; ww < 4; ++ww) {
            const f32x4 v = *(const f32x4*)&red[ww][m][n4];
            s.x += v.x; s.y += v.y; s.z += v.z; s.w += v.w;
        }
        const float sc = 1.0f / 64.0f;
        ushort4 o;
        o.x = (unsigned short)f2bf(s.x * sc);
        o.y = (unsigned short)f2bf(s.y * sc);
        o.z = (unsigned short)f2bf(s.z * sc);
        o.w = (unsigned short)f2bf(s.w * sc);
        *(ushort4*)(Gsum + (size_t)b * 65536 + (size_t)(tm + m) * 256 + tn + n4) = o;
    }
    gbar(grpCnt, top, grpRel, grp, 2);

    // ================= Phase 2: zgemm =================
    {
        const int t = bid & 15;
        const int h = (bid >> 4) & 7;
        const int b = bid >> 7;
        const int tm = (t >> 2) * 64;
        const int tn = (t & 3) * 64;
        const int wm = (w >> 1) * 32, wn = (w & 1) * 32;

        const unsigned short* Qh = Qt + (size_t)h * 65536;
        const unsigned short* Gb = Gsum + (size_t)b * 65536;
        const unsigned short* A0 = Qh + (size_t)(tm + wm + r16) * 256;
        const unsigned short* A1 = A0 + 16 * 256;
        const unsigned short* B0 = Gb + (size_t)(tn + wn + r16) * 256;
        const unsigned short* B1 = B0 + 16 * 256;
        const int k0 = q * 8;

        f32x4 acc[2][2];
#pragma unroll
        for (int mi = 0; mi < 2; ++mi)
#pragma unroll
            for (int ni = 0; ni < 2; ++ni) acc[mi][ni] = (f32x4){0.f,0.f,0.f,0.f};

        bf16x8 aC[2], bC[2];
        aC[0] = *(const bf16x8*)(A0 + k0);
        aC[1] = *(const bf16x8*)(A1 + k0);
        bC[0] = *(const bf16x8*)(B0 + k0);
        bC[1] = *(const bf16x8*)(B1 + k0);

#pragma unroll
        for (int kk = 0; kk < 8; ++kk) {
            bf16x8 aN[2], bN[2];
            if (kk < 7) {
                const int ko = k0 + (kk + 1) * 32;
                aN[0] = *(const bf16x8*)(A0 + ko);
                aN[1] = *(const bf16x8*)(A1 + ko);
                bN[0] = *(const bf16x8*)(B0 + ko);
                bN[1] = *(const bf16x8*)(B1 + ko);
            }
            acc[0][0] = MFMA16(aC[0], bC[0], acc[0][0]);
            acc[0][1] = MFMA16(aC[0], bC[1], acc[0][1]);
            acc[1][0] = MFMA16(aC[1], bC[0], acc[1][0]);
            acc[1][1] = MFMA16(aC[1], bC[1], acc[1][1]);
            aC[0] = aN[0]; aC[1] = aN[1]; bC[0] = bN[0]; bC[1] = bN[1];
        }

        unsigned short* Zb = Zt + (size_t)b * 256 * 2048;
#pragma unroll
        for (int mi = 0; mi < 2; ++mi)
#pragma unroll
            for (int ni = 0; ni < 2; ++ni)
#pragma unroll
                for (int r = 0; r < 4; ++r) {
                    const int m = tm + wm + mi * 16 + q * 4 + r;       // cq
                    const int n = tn + wn + ni * 16 + r16;             // c'
                    Zb[(size_t)m * 2048 + h * 256 + n] = (unsigned short)f2bf(acc[mi][ni][r]);
                }
    }
    gbar(grpCnt, top, grpRel, grp, 3);

    // ================= Phase 3: ngemm =================
    if (bid < 256) {
        const int t = bid & 63;
        const int b = bid >> 6;
        const int tm = (t >> 3) * 32;         // c
        const int tn = (t & 7) * 32;          // cq

        const unsigned short* Zb = Zt + (size_t)b * 256 * 2048;
        const unsigned short* A0 = P  + (size_t)(tm + r16) * 2048;
        const unsigned short* A1 = A0 + (size_t)16 * 2048;
        const unsigned short* B0 = Zb + (size_t)(tn + r16) * 2048;
        const unsigned short* B1 = B0 + (size_t)16 * 2048;
        const int k0 = w * 512 + q * 8;

        f32x4 acc[2][2];
#pragma unroll
        for (int mi = 0; mi < 2; ++mi)
#pragma unroll
            for (int ni = 0; ni < 2; ++ni) acc[mi][ni] = (f32x4){0.f,0.f,0.f,0.f};

        bf16x8 aC[2], bC[2];
        aC[0] = *(const bf16x8*)(A0 + k0);
        aC[1] = *(const bf16x8*)(A1 + k0);
        bC[0] = *(const bf16x8*)(B0 + k0);
        bC[1] = *(const bf16x8*)(B1 + k0);

#pragma unroll
        for (int kk = 0; kk < 16; ++kk) {
            bf16x8 aN[2], bN[2];
            if (kk < 15) {
                const int ko = k0 + (kk + 1) * 32;
                aN[0] = *(const bf16x8*)(A0 + ko);
                aN[1] = *(const bf16x8*)(A1 + ko);
                bN[0] = *(const bf16x8*)(B0 + ko);
                bN[1] = *(const bf16x8*)(B1 + ko);
            }
            acc[0][0] = MFMA16(aC[0], bC[0], acc[0][0]);
            acc[0][1] = MFMA16(aC[0], bC[1], acc[0][1]);
            acc[1][0] = MFMA16(aC[1], bC[0], acc[1][0]);
            acc[1][1] = MFMA16(aC[1], bC[1], acc[1][1]);
            aC[0] = aN[0]; aC[1] = aN[1]; bC[0] = bN[0]; bC[1] = bN[1];
        }

        float (*red)[32][36] = (float(*)[32][36])smem;
        __syncthreads();    // smem reuse guard
#pragma unroll
        for (int mi = 0; mi < 2; ++mi)
#pragma unroll
            for (int ni = 0; ni < 2; ++ni)
#pragma unroll
                for (int r = 0; r < 4; ++r)
                    red[w][mi * 16 + q * 4 + r][ni * 16 + r16] = acc[mi][ni][r];
        __syncthreads();

        const int m  = tid >> 3;              // c
        const int n4 = (tid & 7) * 4;         // cq
        f32x4 s = *(const f32x4*)&red[0][m][n4];
#pragma unroll
        for (int ww = 1; ww < 4; ++ww) {
            const f32x4 v = *(const f32x4*)&red[ww][m][n4];
            s.x += v.x; s.y += v.y; s.z += v.z; s.w += v.w;
        }
        ushort4 o;
        o.x = (unsigned short)f2bf(s.x);
        o.y = (unsigned short)f2bf(s.y);
        o.z = (unsigned short)f2bf(s.z);
        o.w = (unsigned short)f2bf(s.w);
        *(ushort4*)(Nbf + (size_t)b * 65536 + (size_t)(tm + m) * 256 + tn + n4) = o;
    }
    gbar(grpCnt, top, grpRel, grp, 4);

    // ================= Phase 4: final =================
    {
        const int nblk = (bid & 31) * 64;
        const int cblk = ((bid >> 5) & 3) * 64;
        const int b    = bid >> 7;
        const int wc = (w >> 1) * 32;
        const int wn = (w & 1) * 32;

        const unsigned short* Nb = Nbf + (size_t)b * 65536;
        const unsigned short* Xq = xqt_bf + (size_t)b * NQ_ * CQ_;
        const float* Xb = x_q + (size_t)b * CQ_ * NQ_;
        const float g = gamma[0];

        const unsigned short* A0 = Nb + (size_t)(cblk + wc + r16) * 256;
        const unsigned short* A1 = A0 + 16 * 256;
        const unsigned short* B0 = Xq + (size_t)(nblk + wn + r16) * 256;
        const unsigned short* B1 = B0 + 16 * 256;
        const int k0 = q * 8;

        f32x4 acc[2][2];
#pragma unroll
        for (int mi = 0; mi < 2; ++mi)
#pragma unroll
            for (int ni = 0; ni < 2; ++ni) acc[mi][ni] = (f32x4){0.f,0.f,0.f,0.f};

        bf16x8 aC[2], bC[2];
        aC[0] = *(const bf16x8*)(A0 + k0);
        aC[1] = *(const bf16x8*)(A1 + k0);
        bC[0] = *(const bf16x8*)(B0 + k0);
        bC[1] = *(const bf16x8*)(B1 + k0);

#pragma unroll
        for (int kk = 0; kk < 8; ++kk) {
            bf16x8 aN[2], bN[2];
            if (kk < 7) {
                const int ko = k0 + (kk + 1) * 32;
                aN[0] = *(const bf16x8*)(A0 + ko);
                aN[1] = *(const bf16x8*)(A1 + ko);
                bN[0] = *(const bf16x8*)(B0 + ko);
                bN[1] = *(const bf16x8*)(B1 + ko);
            }
            acc[0][0] = MFMA16(aC[0], bC[0], acc[0][0]);
            acc[0][1] = MFMA16(aC[0], bC[1], acc[0][1]);
            acc[1][0] = MFMA16(aC[1], bC[0], acc[1][0]);
            acc[1][1] = MFMA16(aC[1], bC[1], acc[1][1]);
            aC[0] = aN[0]; aC[1] = aN[1]; bC[0] = bN[0]; bC[1] = bN[1];
        }

#pragma unroll
        for (int mi = 0; mi < 2; ++mi)
#pragma unroll
            for (int ni = 0; ni < 2; ++ni)
#pragma unroll
                for (int r = 0; r < 4; ++r) {
                    const int c = cblk + wc + mi * 16 + q * 4 + r;
                    const int n = nblk + wn + ni * 16 + r16;
                    const size_t idx = ((size_t)b * CQ_ + c) * NQ_ + n;
                    out[idx] = g * acc[mi][ni][r] + Xb[(size_t)c * NQ_ + n];
                }
    }
}

// -------------------------------------------------------------------------
extern "C" void kernel_launch(void* const* d_in, const int* in_sizes, int n_in,
                              void* d_out, int out_size, void* d_ws, size_t ws_size,
                              hipStream_t stream) {
    const float* x_q   = (const float*)d_in[0];
    const float* x_kv  = (const float*)d_in[1];
    const float* Wq    = (const float*)d_in[2];
    const float* Wk    = (const float*)d_in[3];
    const float* Wv    = (const float*)d_in[4];
    const float* Wo    = (const float*)d_in[5];
    const float* gamma = (const float*)d_in[6];
    float* out = (float*)d_out;

    char* ws = (char*)d_ws;
    // ws layout (bytes):
    //   xkv_bf bf16 [4][256][2048]        0 ..  4194304
    //   xqt_bf bf16 [4][2048][256]  4194304 ..  8388608
    //   Gsum   bf16 [4][256][256]   8388608 ..  8912896
    //   P      bf16 [256][2048]     8912896 ..  9961472
    //   Qt     bf16 [2048][256]     9961472 .. 11010048
    //   Zt     bf16 [4][256][2048] 11010048 .. 15204352
    //   Nbf    bf16 [4][256][256]  15204352 .. 15728640
    //   barrier block at 16252928: grpCnt[16 x 128B] | top[128B] | grpRel[16 x 128B]
    unsigned short* xkv_bf = (unsigned short*)(ws);
    unsigned short* xqt_bf = (unsigned short*)(ws + 4194304);
    unsigned short* Gsum   = (unsigned short*)(ws + 8388608);
    unsigned short* P      = (unsigned short*)(ws + 8912896);
    unsigned short* Qt     = (unsigned short*)(ws + 9961472);
    unsigned short* Zt     = (unsigned short*)(ws + 11010048);
    unsigned short* Nbf    = (unsigned short*)(ws + 15204352);
    unsigned*       grpCnt = (unsigned*)(ws + 16252928);
    unsigned*       top    = (unsigned*)(ws + 16252928 + 2048);
    unsigned*       grpRel = (unsigned*)(ws + 16252928 + 2048 + 128);

    hipMemsetAsync((void*)(ws + 16252928), 0, 8192, stream);
    fused_kernel<<<dim3(512), dim3(256), 0, stream>>>(
        x_q, x_kv, Wq, Wk, Wv, Wo, gamma, out,
        xkv_bf, xqt_bf, P, Qt, Gsum, Zt, Nbf, grpCnt, top, grpRel);
}

// Round 5
// 156.876 us; speedup vs baseline: 2.8483x; 2.8483x over previous
//
#include <hip/hip_runtime.h>
#include <stdint.h>

// Problem constants
#define B_    4
#define CQ_   256
#define CKV_  256
#define NQ_   2048
#define NKV_  2048
#define H_    8
#define DK_   64
#define HD_   512   // H_*DK_

typedef __attribute__((ext_vector_type(8))) short bf16x8;
typedef __attribute__((ext_vector_type(4))) float f32x4;

__device__ __forceinline__ short f2bf(float f) {
    unsigned u = __builtin_bit_cast(unsigned, f);
    u = (u + 0x7FFFu + ((u >> 16) & 1u)) >> 16;   // RNE truncate to bf16
    return (short)u;
}

#define MFMA16(a, b, c) __builtin_amdgcn_mfma_f32_16x16x32_bf16((a), (b), (c), 0, 0, 0)

// -------------------------------------------------------------------------
// Kernel 1: prep (independent work, block-range dispatch).
//  [0,1024):    x_kv f32 -> xkv_bf bf16 (same layout)
//  [1024,1536): x_q [b][cq][n] -> xqt_bf [b][n][cq] (transpose, bf16)
//  [1536,1568): Wq [512][256] -> WqT [256][512] (transpose, bf16)
// -------------------------------------------------------------------------
__global__ __launch_bounds__(256) void prep_kernel(
    const float* __restrict__ x_kv,
    const float* __restrict__ x_q,
    const float* __restrict__ Wq,
    unsigned short* __restrict__ xkv_bf,
    unsigned short* __restrict__ xqt_bf,
    unsigned short* __restrict__ WqT)
{
    const int tid = threadIdx.x;
    int bid = blockIdx.x;
    __shared__ float tile[64][65];

    if (bid < 1024) {
        const size_t base = ((size_t)bid * 256 + tid) * 8;
        const f32x4 v0 = *(const f32x4*)(x_kv + base);
        const f32x4 v1 = *(const f32x4*)(x_kv + base + 4);
        bf16x8 o;
        o[0] = f2bf(v0.x); o[1] = f2bf(v0.y); o[2] = f2bf(v0.z); o[3] = f2bf(v0.w);
        o[4] = f2bf(v1.x); o[5] = f2bf(v1.y); o[6] = f2bf(v1.z); o[7] = f2bf(v1.w);
        *(bf16x8*)(xkv_bf + base) = o;
        return;
    }
    if (bid < 1536) {
        bid -= 1024;                      // 512 transpose blocks
        const int b   = bid >> 7;
        const int t   = bid & 127;
        const int cq0 = (t & 3) * 64;
        const int n0  = (t >> 2) * 64;

        const float* src = x_q + (size_t)b * CQ_ * NQ_;
        const int r_l = tid >> 4;
        const int c_l = (tid & 15) * 4;
#pragma unroll
        for (int i = 0; i < 4; ++i) {
            const int row = r_l + 16 * i;
            const f32x4 v = *(const f32x4*)(src + (size_t)(cq0 + row) * NQ_ + n0 + c_l);
            tile[row][c_l] = v.x; tile[row][c_l + 1] = v.y;
            tile[row][c_l + 2] = v.z; tile[row][c_l + 3] = v.w;
        }
        __syncthreads();
        unsigned short* dst = xqt_bf + (size_t)b * NQ_ * CQ_;
        const int cq_l = (tid & 7) * 8;
#pragma unroll
        for (int j = 0; j < 2; ++j) {
            const int n_l = (tid >> 3) + 32 * j;
            bf16x8 o;
#pragma unroll
            for (int k = 0; k < 8; ++k) o[k] = f2bf(tile[cq_l + k][n_l]);
            *(bf16x8*)(dst + (size_t)(n0 + n_l) * CQ_ + cq0 + cq_l) = o;
        }
        return;
    }

    // ---- WqT: Wq[o=512][cq=256] -> WqT[cq=256][o=512] bf16 ----
    bid -= 1536;                          // 0..31
    const int o0  = (bid >> 2) * 64;
    const int cq0 = (bid & 3) * 64;
    const int r_l = tid >> 4;
    const int c_l = (tid & 15) * 4;
#pragma unroll
    for (int i = 0; i < 4; ++i) {
        const int row = r_l + 16 * i;     // o_local
        const f32x4 v = *(const f32x4*)(Wq + (size_t)(o0 + row) * 256 + cq0 + c_l);
        tile[row][c_l] = v.x; tile[row][c_l + 1] = v.y;
        tile[row][c_l + 2] = v.z; tile[row][c_l + 3] = v.w;
    }
    __syncthreads();
    const int o_l8 = (tid & 7) * 8;
#pragma unroll
    for (int j = 0; j < 2; ++j) {
        const int cq_l = (tid >> 3) + 32 * j;
        bf16x8 o;
#pragma unroll
        for (int k = 0; k < 8; ++k) o[k] = f2bf(tile[o_l8 + k][cq_l]);
        *(bf16x8*)(WqT + (size_t)(cq0 + cq_l) * 512 + o0 + o_l8) = o;
    }
}

// -------------------------------------------------------------------------
// Kernel 2: Gram, full-K in one block.  32x32 tiles, grid (64,4)=256 blocks.
// Wave w handles K-chunk [w*512,(w+1)*512); partials reduced through LDS.
// G[b][c][c'] = (1/64) * sum_n x[c][n]*x[c'][n]  -> bf16.
// (byte-identical to the verified round-1 kernel)
// -------------------------------------------------------------------------
__global__ __launch_bounds__(256) void gram_kernel(
    const unsigned short* __restrict__ xkv_bf,
    unsigned short* __restrict__ Gsum)
{
    const int t  = blockIdx.x;            // 0..63
    const int b  = blockIdx.y;
    const int tid = threadIdx.x;
    const int w = tid >> 6, L = tid & 63;
    const int r16 = L & 15, q = L >> 4;
    const int tm = (t >> 3) * 32;
    const int tn = (t & 7) * 32;

    const unsigned short* Xb = xkv_bf + (size_t)b * CKV_ * NKV_;
    const unsigned short* A0 = Xb + (size_t)(tm + r16) * NKV_;
    const unsigned short* A1 = A0 + (size_t)16 * NKV_;
    const unsigned short* B0 = Xb + (size_t)(tn + r16) * NKV_;
    const unsigned short* B1 = B0 + (size_t)16 * NKV_;
    const int k0 = w * 512 + q * 8;

    f32x4 acc[2][2];
#pragma unroll
    for (int mi = 0; mi < 2; ++mi)
#pragma unroll
        for (int ni = 0; ni < 2; ++ni) acc[mi][ni] = (f32x4){0.f,0.f,0.f,0.f};

    bf16x8 aC[2], bC[2];
    aC[0] = *(const bf16x8*)(A0 + k0);
    aC[1] = *(const bf16x8*)(A1 + k0);
    bC[0] = *(const bf16x8*)(B0 + k0);
    bC[1] = *(const bf16x8*)(B1 + k0);

#pragma unroll
    for (int kk = 0; kk < 16; ++kk) {
        bf16x8 aN[2], bN[2];
        if (kk < 15) {
            const int ko = k0 + (kk + 1) * 32;
            aN[0] = *(const bf16x8*)(A0 + ko);
            aN[1] = *(const bf16x8*)(A1 + ko);
            bN[0] = *(const bf16x8*)(B0 + ko);
            bN[1] = *(const bf16x8*)(B1 + ko);
        }
        acc[0][0] = MFMA16(aC[0], bC[0], acc[0][0]);
        acc[0][1] = MFMA16(aC[0], bC[1], acc[0][1]);
        acc[1][0] = MFMA16(aC[1], bC[0], acc[1][0]);
        acc[1][1] = MFMA16(aC[1], bC[1], acc[1][1]);
        aC[0] = aN[0]; aC[1] = aN[1]; bC[0] = bN[0]; bC[1] = bN[1];
    }

    __shared__ float red[4][32][36];
#pragma unroll
    for (int mi = 0; mi < 2; ++mi)
#pragma unroll
        for (int ni = 0; ni < 2; ++ni)
#pragma unroll
            for (int r = 0; r < 4; ++r)
                red[w][mi * 16 + q * 4 + r][ni * 16 + r16] = acc[mi][ni][r];
    __syncthreads();

    const int m  = tid >> 3;              // 0..31
    const int n4 = (tid & 7) * 4;         // 0..28
    f32x4 s = *(const f32x4*)&red[0][m][n4];
#pragma unroll
    for (int ww = 1; ww < 4; ++ww) {
        const f32x4 v = *(const f32x4*)&red[ww][m][n4];
        s.x += v.x; s.y += v.y; s.z += v.z; s.w += v.w;
    }
    const float sc = 1.0f / 64.0f;
    ushort4 o;
    o.x = (unsigned short)f2bf(s.x * sc);
    o.y = (unsigned short)f2bf(s.y * sc);
    o.z = (unsigned short)f2bf(s.z * sc);
    o.w = (unsigned short)f2bf(s.w * sc);
    *(ushort4*)(Gsum + (size_t)b * 65536 + (size_t)(tm + m) * 256 + tn + n4) = o;
}

// -------------------------------------------------------------------------
// Kernel 3: echain.  Per (b,h) block:  Epart[b,h] = Wo_h (Wv_h G_b Wk_h^T) Wq_h
// Chain of 4 small GEMMs staged in LDS; f32 output partials.
//   A: T1t[d][c']  = sum_c'' Wk_h[d][c'']  G_b[c'][c'']     (64x256, K=256)
//   B: T2 [d][d']  = sum_c'  Wv_h[d][c']   T1t[d'][c']      (64x64,  K=256) -> store T2t[d'][d]
//   C: T3 [c][d']  = sum_d   Wo[c][h64+d]  T2t[d'][d]       (256x64, K=64)
//   D: Ep [c][cq]  = sum_d'  T3[c][d']     WqT[cq][h64+d']  (256x256,K=64)
// grid (8,4)=32 blocks x 256 threads.
// -------------------------------------------------------------------------
__global__ __launch_bounds__(256) void echain_kernel(
    const unsigned short* __restrict__ Gsum,   // [4][256][256] bf16 (has /64)
    const float* __restrict__ Wk,              // [512][256]
    const float* __restrict__ Wv,              // [512][256]
    const float* __restrict__ Wo,              // [256][512]
    const unsigned short* __restrict__ WqT,    // [256][512] bf16
    float* __restrict__ Epart)                 // [32][256][256] f32
{
    const int h = blockIdx.x;     // 0..7
    const int b = blockIdx.y;     // 0..3
    const int tid = threadIdx.x;
    const int w = tid >> 6, L = tid & 63;
    const int r16 = L & 15, q = L >> 4;

    // union region: T1t[64][264] (33792 u16) aliased by T3[256][72] (18432 u16)
    __shared__ __align__(16) unsigned short T1T3[64 * 264];
    __shared__ __align__(16) unsigned short T2t[64 * 72];

    const unsigned short* Gb = Gsum + (size_t)b * 65536;

    // ---- Stage A: T1t[d][c'] (wave w owns d-rows w*16..w*16+15) ----
    {
        const int m = w * 16 + r16;
        const float* wkrow = Wk + (size_t)(h * 64 + m) * 256;
        f32x4 acc[16];
#pragma unroll
        for (int ni = 0; ni < 16; ++ni) acc[ni] = (f32x4){0.f,0.f,0.f,0.f};
#pragma unroll
        for (int kk = 0; kk < 8; ++kk) {
            const int k0 = kk * 32 + q * 8;
            const f32x4 v0 = *(const f32x4*)(wkrow + k0);
            const f32x4 v1 = *(const f32x4*)(wkrow + k0 + 4);
            bf16x8 a;
            a[0]=f2bf(v0.x); a[1]=f2bf(v0.y); a[2]=f2bf(v0.z); a[3]=f2bf(v0.w);
            a[4]=f2bf(v1.x); a[5]=f2bf(v1.y); a[6]=f2bf(v1.z); a[7]=f2bf(v1.w);
#pragma unroll
            for (int ni = 0; ni < 16; ++ni) {
                const bf16x8 bb = *(const bf16x8*)(Gb + (size_t)(ni * 16 + r16) * 256 + k0);
                acc[ni] = MFMA16(a, bb, acc[ni]);
            }
        }
#pragma unroll
        for (int ni = 0; ni < 16; ++ni)
#pragma unroll
            for (int r = 0; r < 4; ++r)
                T1T3[(w * 16 + q * 4 + r) * 264 + ni * 16 + r16] =
                    (unsigned short)f2bf(acc[ni][r]);
    }
    __syncthreads();

    // ---- Stage B: T2[d][d'] -> T2t[d'][d] ----
    {
        const int m = w * 16 + r16;
        const float* wvrow = Wv + (size_t)(h * 64 + m) * 256;
        f32x4 acc[4];
#pragma unroll
        for (int ni = 0; ni < 4; ++ni) acc[ni] = (f32x4){0.f,0.f,0.f,0.f};
#pragma unroll
        for (int kk = 0; kk < 8; ++kk) {
            const int k0 = kk * 32 + q * 8;
            const f32x4 v0 = *(const f32x4*)(wvrow + k0);
            const f32x4 v1 = *(const f32x4*)(wvrow + k0 + 4);
            bf16x8 a;
            a[0]=f2bf(v0.x); a[1]=f2bf(v0.y); a[2]=f2bf(v0.z); a[3]=f2bf(v0.w);
            a[4]=f2bf(v1.x); a[5]=f2bf(v1.y); a[6]=f2bf(v1.z); a[7]=f2bf(v1.w);
#pragma unroll
            for (int ni = 0; ni < 4; ++ni) {
                const bf16x8 bb = *(const bf16x8*)&T1T3[(ni * 16 + r16) * 264 + k0];
                acc[ni] = MFMA16(a, bb, acc[ni]);
            }
        }
        __syncthreads();   // all T1t reads done before T3 overwrites the union
#pragma unroll
        for (int ni = 0; ni < 4; ++ni)
#pragma unroll
            for (int r = 0; r < 4; ++r)
                T2t[(ni * 16 + r16) * 72 + w * 16 + q * 4 + r] =
                    (unsigned short)f2bf(acc[ni][r]);
    }
    __syncthreads();

    // ---- Stage C: T3[c][d'] (wave w owns c-rows w*64..w*64+63) ----
    {
        const int mbase = w * 64;
        f32x4 acc[4][4];
#pragma unroll
        for (int mi = 0; mi < 4; ++mi)
#pragma unroll
            for (int ni = 0; ni < 4; ++ni) acc[mi][ni] = (f32x4){0.f,0.f,0.f,0.f};
#pragma unroll
        for (int kk = 0; kk < 2; ++kk) {
            const int k0 = kk * 32 + q * 8;
            bf16x8 a[4];
#pragma unroll
            for (int mi = 0; mi < 4; ++mi) {
                const float* worow = Wo + (size_t)(mbase + mi * 16 + r16) * 512 + h * 64;
                const f32x4 v0 = *(const f32x4*)(worow + k0);
                const f32x4 v1 = *(const f32x4*)(worow + k0 + 4);
                a[mi][0]=f2bf(v0.x); a[mi][1]=f2bf(v0.y); a[mi][2]=f2bf(v0.z); a[mi][3]=f2bf(v0.w);
                a[mi][4]=f2bf(v1.x); a[mi][5]=f2bf(v1.y); a[mi][6]=f2bf(v1.z); a[mi][7]=f2bf(v1.w);
            }
#pragma unroll
            for (int ni = 0; ni < 4; ++ni) {
                const bf16x8 bb = *(const bf16x8*)&T2t[(ni * 16 + r16) * 72 + k0];
#pragma unroll
                for (int mi = 0; mi < 4; ++mi)
                    acc[mi][ni] = MFMA16(a[mi], bb, acc[mi][ni]);
            }
        }
        // write T3[c][d'] into the union region, [256][72]
#pragma unroll
        for (int mi = 0; mi < 4; ++mi)
#pragma unroll
            for (int ni = 0; ni < 4; ++ni)
#pragma unroll
                for (int r = 0; r < 4; ++r)
                    T1T3[(mbase + mi * 16 + q * 4 + r) * 72 + ni * 16 + r16] =
                        (unsigned short)f2bf(acc[mi][ni][r]);
    }
    __syncthreads();

    // ---- Stage D: Ep[c][cq] (wave w owns c-rows w*64..; mi-loop bounds VGPR) ----
    {
        const int mbase = w * 64;
        float* Ep = Epart + (size_t)(b * 8 + h) * 65536;
#pragma unroll
        for (int mi = 0; mi < 4; ++mi) {
            f32x4 acc[16];
#pragma unroll
            for (int ni = 0; ni < 16; ++ni) acc[ni] = (f32x4){0.f,0.f,0.f,0.f};
#pragma unroll
            for (int kk = 0; kk < 2; ++kk) {
                const int k0 = kk * 32 + q * 8;
                const bf16x8 a =
                    *(const bf16x8*)&T1T3[(mbase + mi * 16 + r16) * 72 + k0];
#pragma unroll
                for (int ni = 0; ni < 16; ++ni) {
                    const bf16x8 bb =
                        *(const bf16x8*)(WqT + (size_t)(ni * 16 + r16) * 512 + h * 64 + k0);
                    acc[ni] = MFMA16(a, bb, acc[ni]);
                }
            }
#pragma unroll
            for (int ni = 0; ni < 16; ++ni)
#pragma unroll
                for (int r = 0; r < 4; ++r)
                    Ep[(size_t)(mbase + mi * 16 + q * 4 + r) * 256 + ni * 16 + r16]
                        = acc[ni][r];
        }
    }
}

// -------------------------------------------------------------------------
// Kernel 4: reduce Epart over h -> E bf16.  grid 256 x 256 thr.
// -------------------------------------------------------------------------
__global__ __launch_bounds__(256) void ereduce_kernel(
    const float* __restrict__ Epart,
    unsigned short* __restrict__ E)
{
    const int idx4 = blockIdx.x * 256 + threadIdx.x;   // 0..65535
    const int b = idx4 >> 14;                          // 16384 f32x4 per batch
    const size_t off = (size_t)(idx4 & 16383) * 4;
    const float* base = Epart + (size_t)b * 8 * 65536 + off;
    f32x4 s = (f32x4){0.f,0.f,0.f,0.f};
#pragma unroll
    for (int hh = 0; hh < 8; ++hh) {
        const f32x4 v = *(const f32x4*)(base + (size_t)hh * 65536);
        s.x += v.x; s.y += v.y; s.z += v.z; s.w += v.w;
    }
    ushort4 o;
    o.x = (unsigned short)f2bf(s.x);
    o.y = (unsigned short)f2bf(s.y);
    o.z = (unsigned short)f2bf(s.z);
    o.w = (unsigned short)f2bf(s.w);
    *(ushort4*)(E + (size_t)b * 65536 + off) = o;
}

// -------------------------------------------------------------------------
// Kernel 5: final.  out[b][c][n] = g*sum_cq E[b][c][cq]*xqt[b][n][cq] + x_q[b][c][n]
// 64x64 tiles, grid (32,4,4)=512 blocks.  (byte-identical to round-1 final)
// -------------------------------------------------------------------------
__global__ __launch_bounds__(256) void final_kernel(
    const unsigned short* __restrict__ E,
    const unsigned short* __restrict__ xqt_bf,
    const float* __restrict__ x_q,
    const float* __restrict__ gamma,
    float* __restrict__ out)
{
    const int nblk = blockIdx.x * 64;
    const int cblk = blockIdx.y * 64;
    const int b    = blockIdx.z;
    const int tid  = threadIdx.x;
    const int w = tid >> 6, L = tid & 63;
    const int r16 = L & 15, q = L >> 4;
    const int wc = (w >> 1) * 32;
    const int wn = (w & 1) * 32;

    const unsigned short* Nb = E + (size_t)b * 65536;
    const unsigned short* Xq = xqt_bf + (size_t)b * NQ_ * CQ_;
    const float* Xb = x_q + (size_t)b * CQ_ * NQ_;
    const float g = gamma[0];

    const unsigned short* A0 = Nb + (size_t)(cblk + wc + r16) * 256;
    const unsigned short* A1 = A0 + 16 * 256;
    const unsigned short* B0 = Xq + (size_t)(nblk + wn + r16) * 256;
    const unsigned short* B1 = B0 + 16 * 256;
    const int k0 = q * 8;

    f32x4 acc[2][2];
#pragma unroll
    for (int mi = 0; mi < 2; ++mi)
#pragma unroll
        for (int ni = 0; ni < 2; ++ni) acc[mi][ni] = (f32x4){0.f,0.f,0.f,0.f};

    bf16x8 aC[2], bC[2];
    aC[0] = *(const bf16x8*)(A0 + k0);
    aC[1] = *(const bf16x8*)(A1 + k0);
    bC[0] = *(const bf16x8*)(B0 + k0);
    bC[1] = *(const bf16x8*)(B1 + k0);

#pragma unroll
    for (int kk = 0; kk < 8; ++kk) {
        bf16x8 aN[2], bN[2];
        if (kk < 7) {
            const int ko = k0 + (kk + 1) * 32;
            aN[0] = *(const bf16x8*)(A0 + ko);
            aN[1] = *(const bf16x8*)(A1 + ko);
            bN[0] = *(const bf16x8*)(B0 + ko);
            bN[1] = *(const bf16x8*)(B1 + ko);
        }
        acc[0][0] = MFMA16(aC[0], bC[0], acc[0][0]);
        acc[0][1] = MFMA16(aC[0], bC[1], acc[0][1]);
        acc[1][0] = MFMA16(aC[1], bC[0], acc[1][0]);
        acc[1][1] = MFMA16(aC[1], bC[1], acc[1][1]);
        aC[0] = aN[0]; aC[1] = aN[1]; bC[0] = bN[0]; bC[1] = bN[1];
    }

#pragma unroll
    for (int mi = 0; mi < 2; ++mi)
#pragma unroll
        for (int ni = 0; ni < 2; ++ni)
#pragma unroll
            for (int r = 0; r < 4; ++r) {
                const int c = cblk + wc + mi * 16 + q * 4 + r;
                const int n = nblk + wn + ni * 16 + r16;
                const size_t idx = ((size_t)b * CQ_ + c) * NQ_ + n;
                out[idx] = g * acc[mi][ni][r] + Xb[(size_t)c * NQ_ + n];
            }
}

// -------------------------------------------------------------------------
extern "C" void kernel_launch(void* const* d_in, const int* in_sizes, int n_in,
                              void* d_out, int out_size, void* d_ws, size_t ws_size,
                              hipStream_t stream) {
    const float* x_q   = (const float*)d_in[0];
    const float* x_kv  = (const float*)d_in[1];
    const float* Wq    = (const float*)d_in[2];
    const float* Wk    = (const float*)d_in[3];
    const float* Wv    = (const float*)d_in[4];
    const float* Wo    = (const float*)d_in[5];
    const float* gamma = (const float*)d_in[6];
    float* out = (float*)d_out;

    char* ws = (char*)d_ws;
    // ws layout (bytes):
    //   xkv_bf bf16 [4][256][2048]        0 ..  4194304
    //   xqt_bf bf16 [4][2048][256]  4194304 ..  8388608
    //   Gsum   bf16 [4][256][256]   8388608 ..  8912896
    //   WqT    bf16 [256][512]      8912896 ..  9175040
    //   Epart  f32  [32][256][256]  9175040 .. 17563648
    //   E      bf16 [4][256][256]  17563648 .. 18087936
    unsigned short* xkv_bf = (unsigned short*)(ws);
    unsigned short* xqt_bf = (unsigned short*)(ws + 4194304);
    unsigned short* Gsum   = (unsigned short*)(ws + 8388608);
    unsigned short* WqT    = (unsigned short*)(ws + 8912896);
    float*          Epart  = (float*)(ws + 9175040);
    unsigned short* E      = (unsigned short*)(ws + 17563648);

    prep_kernel<<<dim3(1568), 256, 0, stream>>>(x_kv, x_q, Wq, xkv_bf, xqt_bf, WqT);
    gram_kernel<<<dim3(64, 4), 256, 0, stream>>>(xkv_bf, Gsum);
    echain_kernel<<<dim3(8, 4), 256, 0, stream>>>(Gsum, Wk, Wv, Wo, WqT, Epart);
    ereduce_kernel<<<dim3(256), 256, 0, stream>>>(Epart, E);
    final_kernel<<<dim3(32, 4, 4), 256, 0, stream>>>(E, xqt_bf, x_q, gamma, out);
}

// Round 6
// 123.541 us; speedup vs baseline: 3.6168x; 1.2698x over previous
//
#include <hip/hip_runtime.h>
#include <stdint.h>

// Problem constants
#define B_    4
#define CQ_   256
#define CKV_  256
#define NQ_   2048
#define NKV_  2048
#define H_    8
#define DK_   64
#define HD_   512   // H_*DK_

typedef __attribute__((ext_vector_type(8))) short bf16x8;
typedef __attribute__((ext_vector_type(4))) float f32x4;

__device__ __forceinline__ short f2bf(float f) {
    unsigned u = __builtin_bit_cast(unsigned, f);
    u = (u + 0x7FFFu + ((u >> 16) & 1u)) >> 16;   // RNE truncate to bf16
    return (short)u;
}

__device__ __forceinline__ bf16x8 cvt8(const float* p) {
    const f32x4 v0 = *(const f32x4*)p;
    const f32x4 v1 = *(const f32x4*)(p + 4);
    bf16x8 o;
    o[0] = f2bf(v0.x); o[1] = f2bf(v0.y); o[2] = f2bf(v0.z); o[3] = f2bf(v0.w);
    o[4] = f2bf(v1.x); o[5] = f2bf(v1.y); o[6] = f2bf(v1.z); o[7] = f2bf(v1.w);
    return o;
}

#define MFMA16(a, b, c) __builtin_amdgcn_mfma_f32_16x16x32_bf16((a), (b), (c), 0, 0, 0)

// -------------------------------------------------------------------------
// Kernel 1: prep + pq fused (independent work, block-range dispatch).
//  [0,512):   x_q [b][cq][n] -> xqt_bf [b][n][cq] (transpose, bf16)
//  [512,640): pq folds:
//     bid-512 <64:  P[c][h*256+c'] = sum_d Wo[c][h64+d]*Wv[h64+d][c']
//     else:         Qt[h*256+cq][c''] = sum_d Wk[h64+d][c'']*Wq[h64+d][cq]
//  (x_kv bf16 pass removed: gram converts f32 inline — saves a 24MB round-trip)
// -------------------------------------------------------------------------
__global__ __launch_bounds__(256) void prep_pq_kernel(
    const float* __restrict__ x_q,
    const float* __restrict__ Wq,
    const float* __restrict__ Wk,
    const float* __restrict__ Wv,
    const float* __restrict__ Wo,
    unsigned short* __restrict__ xqt_bf,
    unsigned short* __restrict__ P,
    unsigned short* __restrict__ Qt)
{
    const int tid = threadIdx.x;
    int bid = blockIdx.x;
    if (bid < 512) {
        const int b   = bid >> 7;
        const int t   = bid & 127;
        const int cq0 = (t & 3) * 64;
        const int n0  = (t >> 2) * 64;

        __shared__ float tile[64][65];
        const float* src = x_q + (size_t)b * CQ_ * NQ_;
        const int r_l = tid >> 4;
        const int c_l = (tid & 15) * 4;
#pragma unroll
        for (int i = 0; i < 4; ++i) {
            const int row = r_l + 16 * i;
            const f32x4 v = *(const f32x4*)(src + (size_t)(cq0 + row) * NQ_ + n0 + c_l);
            tile[row][c_l] = v.x; tile[row][c_l + 1] = v.y;
            tile[row][c_l + 2] = v.z; tile[row][c_l + 3] = v.w;
        }
        __syncthreads();
        unsigned short* dst = xqt_bf + (size_t)b * NQ_ * CQ_;
        const int cq_l = (tid & 7) * 8;
#pragma unroll
        for (int j = 0; j < 2; ++j) {
            const int n_l = (tid >> 3) + 32 * j;
            bf16x8 o;
#pragma unroll
            for (int k = 0; k < 8; ++k) o[k] = f2bf(tile[cq_l + k][n_l]);
            *(bf16x8*)(dst + (size_t)(n0 + n_l) * CQ_ + cq0 + cq_l) = o;
        }
        return;
    }

    // ---- pq part ----
    const int lb0 = bid - 512;
    const bool isP = (lb0 < 64);
    const int lb = isP ? lb0 : lb0 - 64;
    const int h = lb >> 3;
    const int t = lb & 7;
    const int tm = (t >> 1) * 64;
    const int tn = (t & 1) * 128;
    const int w = tid >> 6, L = tid & 63;
    const int r16 = L & 15, q = L >> 4;
    const int wm = (w >> 1) * 32, wn = (w & 1) * 64;

    f32x4 acc[2][4];
#pragma unroll
    for (int mi = 0; mi < 2; ++mi)
#pragma unroll
        for (int ni = 0; ni < 4; ++ni) acc[mi][ni] = (f32x4){0.f,0.f,0.f,0.f};

#pragma unroll
    for (int kk = 0; kk < 2; ++kk) {
        const int d0 = kk * 32 + q * 8;
        bf16x8 a[2], bb[4];
        if (isP) {
#pragma unroll
            for (int mi = 0; mi < 2; ++mi) {
                const int m = tm + wm + mi * 16 + r16;
                a[mi] = cvt8(Wo + (size_t)m * HD_ + h * 64 + d0);
            }
#pragma unroll
            for (int ni = 0; ni < 4; ++ni) {
                const int n = tn + wn + ni * 16 + r16;
#pragma unroll
                for (int j = 0; j < 8; ++j)
                    bb[ni][j] = f2bf(Wv[(size_t)(h * 64 + d0 + j) * CKV_ + n]);
            }
        } else {
#pragma unroll
            for (int mi = 0; mi < 2; ++mi) {
                const int m = tm + wm + mi * 16 + r16;
#pragma unroll
                for (int j = 0; j < 8; ++j)
                    a[mi][j] = f2bf(Wq[(size_t)(h * 64 + d0 + j) * CQ_ + m]);
            }
#pragma unroll
            for (int ni = 0; ni < 4; ++ni) {
                const int n = tn + wn + ni * 16 + r16;
#pragma unroll
                for (int j = 0; j < 8; ++j)
                    bb[ni][j] = f2bf(Wk[(size_t)(h * 64 + d0 + j) * CKV_ + n]);
            }
        }
#pragma unroll
        for (int mi = 0; mi < 2; ++mi)
#pragma unroll
            for (int ni = 0; ni < 4; ++ni)
                acc[mi][ni] = MFMA16(a[mi], bb[ni], acc[mi][ni]);
    }

#pragma unroll
    for (int mi = 0; mi < 2; ++mi)
#pragma unroll
        for (int ni = 0; ni < 4; ++ni)
#pragma unroll
            for (int r = 0; r < 4; ++r) {
                const int m = tm + wm + mi * 16 + q * 4 + r;
                const int n = tn + wn + ni * 16 + r16;
                if (isP)  P [(size_t)m * 2048 + h * 256 + n] = (unsigned short)f2bf(acc[mi][ni][r]);
                else      Qt[((size_t)h * 256 + m) * 256 + n] = (unsigned short)f2bf(acc[mi][ni][r]);
            }
}

// -------------------------------------------------------------------------
// Kernel 2: Gram, full-K in one block.  32x32 tiles, grid (64,4)=256 blocks.
// Reads x_kv f32 DIRECTLY, converts inline (prep-0a pass removed).
// Wave w handles K-chunk [w*512,(w+1)*512); partials reduced through LDS.
// G[b][c][c'] = (1/64) * sum_n x[c][n]*x[c'][n]  -> bf16.
// -------------------------------------------------------------------------
__global__ __launch_bounds__(256) void gram_kernel(
    const float* __restrict__ x_kv,
    unsigned short* __restrict__ Gsum)
{
    const int t  = blockIdx.x;            // 0..63
    const int b  = blockIdx.y;
    const int tid = threadIdx.x;
    const int w = tid >> 6, L = tid & 63;
    const int r16 = L & 15, q = L >> 4;
    const int tm = (t >> 3) * 32;
    const int tn = (t & 7) * 32;

    const float* Xb = x_kv + (size_t)b * CKV_ * NKV_;
    const float* A0 = Xb + (size_t)(tm + r16) * NKV_;
    const float* A1 = A0 + (size_t)16 * NKV_;
    const float* B0 = Xb + (size_t)(tn + r16) * NKV_;
    const float* B1 = B0 + (size_t)16 * NKV_;
    const int k0 = w * 512 + q * 8;

    f32x4 acc[2][2];
#pragma unroll
    for (int mi = 0; mi < 2; ++mi)
#pragma unroll
        for (int ni = 0; ni < 2; ++ni) acc[mi][ni] = (f32x4){0.f,0.f,0.f,0.f};

    bf16x8 aC[2], bC[2];
    aC[0] = cvt8(A0 + k0);
    aC[1] = cvt8(A1 + k0);
    bC[0] = cvt8(B0 + k0);
    bC[1] = cvt8(B1 + k0);

#pragma unroll
    for (int kk = 0; kk < 16; ++kk) {
        bf16x8 aN[2], bN[2];
        if (kk < 15) {
            const int ko = k0 + (kk + 1) * 32;
            aN[0] = cvt8(A0 + ko);
            aN[1] = cvt8(A1 + ko);
            bN[0] = cvt8(B0 + ko);
            bN[1] = cvt8(B1 + ko);
        }
        acc[0][0] = MFMA16(aC[0], bC[0], acc[0][0]);
        acc[0][1] = MFMA16(aC[0], bC[1], acc[0][1]);
        acc[1][0] = MFMA16(aC[1], bC[0], acc[1][0]);
        acc[1][1] = MFMA16(aC[1], bC[1], acc[1][1]);
        aC[0] = aN[0]; aC[1] = aN[1]; bC[0] = bN[0]; bC[1] = bN[1];
    }

    __shared__ float red[4][32][36];
#pragma unroll
    for (int mi = 0; mi < 2; ++mi)
#pragma unroll
        for (int ni = 0; ni < 2; ++ni)
#pragma unroll
            for (int r = 0; r < 4; ++r)
                red[w][mi * 16 + q * 4 + r][ni * 16 + r16] = acc[mi][ni][r];
    __syncthreads();

    const int m  = tid >> 3;              // 0..31
    const int n4 = (tid & 7) * 4;         // 0..28
    f32x4 s = *(const f32x4*)&red[0][m][n4];
#pragma unroll
    for (int ww = 1; ww < 4; ++ww) {
        const f32x4 v = *(const f32x4*)&red[ww][m][n4];
        s.x += v.x; s.y += v.y; s.z += v.z; s.w += v.w;
    }
    const float sc = 1.0f / 64.0f;
    ushort4 o;
    o.x = (unsigned short)f2bf(s.x * sc);
    o.y = (unsigned short)f2bf(s.y * sc);
    o.z = (unsigned short)f2bf(s.z * sc);
    o.w = (unsigned short)f2bf(s.w * sc);
    *(ushort4*)(Gsum + (size_t)b * 65536 + (size_t)(tm + m) * 256 + tn + n4) = o;
}

// -------------------------------------------------------------------------
// Kernel 3: zgemm.  Zt_b[cq][h*256+c'] = sum_{c''} Qt[(h,cq)][c'']*Gs_b[c'][c'']
// 64x64 tiles, grid (16,8,4)=512 blocks.  Double-buffered K-loop.
// -------------------------------------------------------------------------
__global__ __launch_bounds__(256) void zgemm_kernel(
    const unsigned short* __restrict__ Qt,
    const unsigned short* __restrict__ Gsum,
    unsigned short* __restrict__ Zt)
{
    const int t = blockIdx.x;   // 0..15
    const int h = blockIdx.y;
    const int b = blockIdx.z;
    const int tid = threadIdx.x;
    const int w = tid >> 6, L = tid & 63;
    const int r16 = L & 15, q = L >> 4;
    const int tm = (t >> 2) * 64;
    const int tn = (t & 3) * 64;
    const int wm = (w >> 1) * 32, wn = (w & 1) * 32;

    const unsigned short* Qh = Qt + (size_t)h * 65536;
    const unsigned short* Gb = Gsum + (size_t)b * 65536;
    const unsigned short* A0 = Qh + (size_t)(tm + wm + r16) * 256;
    const unsigned short* A1 = A0 + 16 * 256;
    const unsigned short* B0 = Gb + (size_t)(tn + wn + r16) * 256;
    const unsigned short* B1 = B0 + 16 * 256;
    const int k0 = q * 8;

    f32x4 acc[2][2];
#pragma unroll
    for (int mi = 0; mi < 2; ++mi)
#pragma unroll
        for (int ni = 0; ni < 2; ++ni) acc[mi][ni] = (f32x4){0.f,0.f,0.f,0.f};

    bf16x8 aC[2], bC[2];
    aC[0] = *(const bf16x8*)(A0 + k0);
    aC[1] = *(const bf16x8*)(A1 + k0);
    bC[0] = *(const bf16x8*)(B0 + k0);
    bC[1] = *(const bf16x8*)(B1 + k0);

#pragma unroll
    for (int kk = 0; kk < 8; ++kk) {
        bf16x8 aN[2], bN[2];
        if (kk < 7) {
            const int ko = k0 + (kk + 1) * 32;
            aN[0] = *(const bf16x8*)(A0 + ko);
            aN[1] = *(const bf16x8*)(A1 + ko);
            bN[0] = *(const bf16x8*)(B0 + ko);
            bN[1] = *(const bf16x8*)(B1 + ko);
        }
        acc[0][0] = MFMA16(aC[0], bC[0], acc[0][0]);
        acc[0][1] = MFMA16(aC[0], bC[1], acc[0][1]);
        acc[1][0] = MFMA16(aC[1], bC[0], acc[1][0]);
        acc[1][1] = MFMA16(aC[1], bC[1], acc[1][1]);
        aC[0] = aN[0]; aC[1] = aN[1]; bC[0] = bN[0]; bC[1] = bN[1];
    }

    unsigned short* Zb = Zt + (size_t)b * 256 * 2048;
#pragma unroll
    for (int mi = 0; mi < 2; ++mi)
#pragma unroll
        for (int ni = 0; ni < 2; ++ni)
#pragma unroll
            for (int r = 0; r < 4; ++r) {
                const int m = tm + wm + mi * 16 + q * 4 + r;       // cq
                const int n = tn + wn + ni * 16 + r16;             // c'
                Zb[(size_t)m * 2048 + h * 256 + n] = (unsigned short)f2bf(acc[mi][ni][r]);
            }
}

// -------------------------------------------------------------------------
// Kernel 4: ngemm, full-K in one block.  N[b][c][cq] = sum_k P[c][k]*Zt_b[cq][k]
// 32x32 tiles, grid (64,4)=256 blocks; wave-level split-K (4x512) + LDS reduce.
// Writes Nbf bf16 directly.
// -------------------------------------------------------------------------
__global__ __launch_bounds__(256) void ngemm_kernel(
    const unsigned short* __restrict__ P,
    const unsigned short* __restrict__ Zt,
    unsigned short* __restrict__ Nbf)
{
    const int t  = blockIdx.x;            // 0..63
    const int b  = blockIdx.y;
    const int tid = threadIdx.x;
    const int w = tid >> 6, L = tid & 63;
    const int r16 = L & 15, q = L >> 4;
    const int tm = (t >> 3) * 32;         // c
    const int tn = (t & 7) * 32;          // cq

    const unsigned short* Zb = Zt + (size_t)b * 256 * 2048;
    const unsigned short* A0 = P  + (size_t)(tm + r16) * 2048;
    const unsigned short* A1 = A0 + (size_t)16 * 2048;
    const unsigned short* B0 = Zb + (size_t)(tn + r16) * 2048;
    const unsigned short* B1 = B0 + (size_t)16 * 2048;
    const int k0 = w * 512 + q * 8;

    f32x4 acc[2][2];
#pragma unroll
    for (int mi = 0; mi < 2; ++mi)
#pragma unroll
        for (int ni = 0; ni < 2; ++ni) acc[mi][ni] = (f32x4){0.f,0.f,0.f,0.f};

    bf16x8 aC[2], bC[2];
    aC[0] = *(const bf16x8*)(A0 + k0);
    aC[1] = *(const bf16x8*)(A1 + k0);
    bC[0] = *(const bf16x8*)(B0 + k0);
    bC[1] = *(const bf16x8*)(B1 + k0);

#pragma unroll
    for (int kk = 0; kk < 16; ++kk) {
        bf16x8 aN[2], bN[2];
        if (kk < 15) {
            const int ko = k0 + (kk + 1) * 32;
            aN[0] = *(const bf16x8*)(A0 + ko);
            aN[1] = *(const bf16x8*)(A1 + ko);
            bN[0] = *(const bf16x8*)(B0 + ko);
            bN[1] = *(const bf16x8*)(B1 + ko);
        }
        acc[0][0] = MFMA16(aC[0], bC[0], acc[0][0]);
        acc[0][1] = MFMA16(aC[0], bC[1], acc[0][1]);
        acc[1][0] = MFMA16(aC[1], bC[0], acc[1][0]);
        acc[1][1] = MFMA16(aC[1], bC[1], acc[1][1]);
        aC[0] = aN[0]; aC[1] = aN[1]; bC[0] = bN[0]; bC[1] = bN[1];
    }

    __shared__ float red[4][32][36];
#pragma unroll
    for (int mi = 0; mi < 2; ++mi)
#pragma unroll
        for (int ni = 0; ni < 2; ++ni)
#pragma unroll
            for (int r = 0; r < 4; ++r)
                red[w][mi * 16 + q * 4 + r][ni * 16 + r16] = acc[mi][ni][r];
    __syncthreads();

    const int m  = tid >> 3;              // 0..31 (c)
    const int n4 = (tid & 7) * 4;         // 0..28 (cq)
    f32x4 s = *(const f32x4*)&red[0][m][n4];
#pragma unroll
    for (int ww = 1; ww < 4; ++ww) {
        const f32x4 v = *(const f32x4*)&red[ww][m][n4];
        s.x += v.x; s.y += v.y; s.z += v.z; s.w += v.w;
    }
    ushort4 o;
    o.x = (unsigned short)f2bf(s.x);
    o.y = (unsigned short)f2bf(s.y);
    o.z = (unsigned short)f2bf(s.z);
    o.w = (unsigned short)f2bf(s.w);
    *(ushort4*)(Nbf + (size_t)b * 65536 + (size_t)(tm + m) * 256 + tn + n4) = o;
}

// -------------------------------------------------------------------------
// Kernel 5: final.  out[b][c][n] = g*sum_cq Nbf[b][c][cq]*xqt[b][n][cq] + x_q[b][c][n]
// 64x64 tiles, grid (32,4,4)=512 blocks.  Double-buffered K-loop.
// -------------------------------------------------------------------------
__global__ __launch_bounds__(256) void final_kernel(
    const unsigned short* __restrict__ Nbf,
    const unsigned short* __restrict__ xqt_bf,
    const float* __restrict__ x_q,
    const float* __restrict__ gamma,
    float* __restrict__ out)
{
    const int nblk = blockIdx.x * 64;
    const int cblk = blockIdx.y * 64;
    const int b    = blockIdx.z;
    const int tid  = threadIdx.x;
    const int w = tid >> 6, L = tid & 63;
    const int r16 = L & 15, q = L >> 4;
    const int wc = (w >> 1) * 32;
    const int wn = (w & 1) * 32;

    const unsigned short* Nb = Nbf + (size_t)b * 65536;
    const unsigned short* Xq = xqt_bf + (size_t)b * NQ_ * CQ_;
    const float* Xb = x_q + (size_t)b * CQ_ * NQ_;
    const float g = gamma[0];

    const unsigned short* A0 = Nb + (size_t)(cblk + wc + r16) * 256;
    const unsigned short* A1 = A0 + 16 * 256;
    const unsigned short* B0 = Xq + (size_t)(nblk + wn + r16) * 256;
    const unsigned short* B1 = B0 + 16 * 256;
    const int k0 = q * 8;

    f32x4 acc[2][2];
#pragma unroll
    for (int mi = 0; mi < 2; ++mi)
#pragma unroll
        for (int ni = 0; ni < 2; ++ni) acc[mi][ni] = (f32x4){0.f,0.f,0.f,0.f};

    bf16x8 aC[2], bC[2];
    aC[0] = *(const bf16x8*)(A0 + k0);
    aC[1] = *(const bf16x8*)(A1 + k0);
    bC[0] = *(const bf16x8*)(B0 + k0);
    bC[1] = *(const bf16x8*)(B1 + k0);

#pragma unroll
    for (int kk = 0; kk < 8; ++kk) {
        bf16x8 aN[2], bN[2];
        if (kk < 7) {
            const int ko = k0 + (kk + 1) * 32;
            aN[0] = *(const bf16x8*)(A0 + ko);
            aN[1] = *(const bf16x8*)(A1 + ko);
            bN[0] = *(const bf16x8*)(B0 + ko);
            bN[1] = *(const bf16x8*)(B1 + ko);
        }
        acc[0][0] = MFMA16(aC[0], bC[0], acc[0][0]);
        acc[0][1] = MFMA16(aC[0], bC[1], acc[0][1]);
        acc[1][0] = MFMA16(aC[1], bC[0], acc[1][0]);
        acc[1][1] = MFMA16(aC[1], bC[1], acc[1][1]);
        aC[0] = aN[0]; aC[1] = aN[1]; bC[0] = bN[0]; bC[1] = bN[1];
    }

#pragma unroll
    for (int mi = 0; mi < 2; ++mi)
#pragma unroll
        for (int ni = 0; ni < 2; ++ni)
#pragma unroll
            for (int r = 0; r < 4; ++r) {
                const int c = cblk + wc + mi * 16 + q * 4 + r;
                const int n = nblk + wn + ni * 16 + r16;
                const size_t idx = ((size_t)b * CQ_ + c) * NQ_ + n;
                out[idx] = g * acc[mi][ni][r] + Xb[(size_t)c * NQ_ + n];
            }
}

// -------------------------------------------------------------------------
extern "C" void kernel_launch(void* const* d_in, const int* in_sizes, int n_in,
                              void* d_out, int out_size, void* d_ws, size_t ws_size,
                              hipStream_t stream) {
    const float* x_q   = (const float*)d_in[0];
    const float* x_kv  = (const float*)d_in[1];
    const float* Wq    = (const float*)d_in[2];
    const float* Wk    = (const float*)d_in[3];
    const float* Wv    = (const float*)d_in[4];
    const float* Wo    = (const float*)d_in[5];
    const float* gamma = (const float*)d_in[6];
    float* out = (float*)d_out;

    char* ws = (char*)d_ws;
    // ws layout (bytes):
    //   xqt_bf bf16 [4][2048][256]        0 ..  4194304
    //   Gsum   bf16 [4][256][256]   4194304 ..  4718592
    //   P      bf16 [256][2048]     4718592 ..  5767168
    //   Qt     bf16 [2048][256]     5767168 ..  6815744
    //   Zt     bf16 [4][256][2048]  6815744 .. 11010048
    //   Nbf    bf16 [4][256][256]  11010048 .. 11534336
    unsigned short* xqt_bf = (unsigned short*)(ws);
    unsigned short* Gsum   = (unsigned short*)(ws + 4194304);
    unsigned short* P      = (unsigned short*)(ws + 4718592);
    unsigned short* Qt     = (unsigned short*)(ws + 5767168);
    unsigned short* Zt     = (unsigned short*)(ws + 6815744);
    unsigned short* Nbf    = (unsigned short*)(ws + 11010048);

    prep_pq_kernel<<<dim3(640), 256, 0, stream>>>(x_q, Wq, Wk, Wv, Wo,
                                                  xqt_bf, P, Qt);
    gram_kernel<<<dim3(64, 4), 256, 0, stream>>>(x_kv, Gsum);
    zgemm_kernel<<<dim3(16, 8, 4), 256, 0, stream>>>(Qt, Gsum, Zt);
    ngemm_kernel<<<dim3(64, 4), 256, 0, stream>>>(P, Zt, Nbf);
    final_kernel<<<dim3(32, 4, 4), 256, 0, stream>>>(Nbf, xqt_bf, x_q, gamma, out);
}

// Round 7
// 117.613 us; speedup vs baseline: 3.7991x; 1.0504x over previous
//
#include <hip/hip_runtime.h>
#include <stdint.h>

// Problem constants
#define B_    4
#define CQ_   256
#define CKV_  256
#define NQ_   2048
#define NKV_  2048
#define H_    8
#define DK_   64
#define HD_   512   // H_*DK_

typedef __attribute__((ext_vector_type(8))) short bf16x8;
typedef __attribute__((ext_vector_type(4))) float f32x4;

__device__ __forceinline__ short f2bf(float f) {
    unsigned u = __builtin_bit_cast(unsigned, f);
    u = (u + 0x7FFFu + ((u >> 16) & 1u)) >> 16;   // RNE truncate to bf16
    return (short)u;
}

__device__ __forceinline__ bf16x8 cvt8(const float* p) {
    const f32x4 v0 = *(const f32x4*)p;
    const f32x4 v1 = *(const f32x4*)(p + 4);
    bf16x8 o;
    o[0] = f2bf(v0.x); o[1] = f2bf(v0.y); o[2] = f2bf(v0.z); o[3] = f2bf(v0.w);
    o[4] = f2bf(v1.x); o[5] = f2bf(v1.y); o[6] = f2bf(v1.z); o[7] = f2bf(v1.w);
    return o;
}

#define MFMA16(a, b, c) __builtin_amdgcn_mfma_f32_16x16x32_bf16((a), (b), (c), 0, 0, 0)

// -------------------------------------------------------------------------
// Kernel 1: gram + pq folds (independent work, block-range dispatch, 384 blk).
//  [0,256):   Gram. 32x32 tiles, (t=bid&63, b=bid>>6). Reads x_kv f32,
//             converts inline. Wave w = K-chunk w*512; LDS split-K reduce.
//             G[b][c][c'] = (1/64) sum_n x[c][n] x[c'][n] -> bf16.
//  [256,384): pq folds:
//     lb<64:  P[c][h*256+c'] = sum_d Wo[c][h64+d]*Wv[h64+d][c']
//     else:   Qt[h*256+cq][c''] = sum_d Wk[h64+d][c'']*Wq[h64+d][cq]
//  (x_q transpose stage removed entirely: final reads x_q f32 directly)
// -------------------------------------------------------------------------
__global__ __launch_bounds__(256) void gram_pq_kernel(
    const float* __restrict__ x_kv,
    const float* __restrict__ Wq,
    const float* __restrict__ Wk,
    const float* __restrict__ Wv,
    const float* __restrict__ Wo,
    unsigned short* __restrict__ Gsum,
    unsigned short* __restrict__ P,
    unsigned short* __restrict__ Qt)
{
    const int tid = threadIdx.x;
    const int bid = blockIdx.x;
    const int w = tid >> 6, L = tid & 63;
    const int r16 = L & 15, q = L >> 4;
    __shared__ float red[4][32][36];

    if (bid < 256) {
        // ---- Gram ----
        const int t = bid & 63;
        const int b = bid >> 6;
        const int tm = (t >> 3) * 32;
        const int tn = (t & 7) * 32;

        const float* Xb = x_kv + (size_t)b * CKV_ * NKV_;
        const float* A0 = Xb + (size_t)(tm + r16) * NKV_;
        const float* A1 = A0 + (size_t)16 * NKV_;
        const float* B0 = Xb + (size_t)(tn + r16) * NKV_;
        const float* B1 = B0 + (size_t)16 * NKV_;
        const int k0 = w * 512 + q * 8;

        f32x4 acc[2][2];
#pragma unroll
        for (int mi = 0; mi < 2; ++mi)
#pragma unroll
            for (int ni = 0; ni < 2; ++ni) acc[mi][ni] = (f32x4){0.f,0.f,0.f,0.f};

        bf16x8 aC[2], bC[2];
        aC[0] = cvt8(A0 + k0);
        aC[1] = cvt8(A1 + k0);
        bC[0] = cvt8(B0 + k0);
        bC[1] = cvt8(B1 + k0);

#pragma unroll
        for (int kk = 0; kk < 16; ++kk) {
            bf16x8 aN[2], bN[2];
            if (kk < 15) {
                const int ko = k0 + (kk + 1) * 32;
                aN[0] = cvt8(A0 + ko);
                aN[1] = cvt8(A1 + ko);
                bN[0] = cvt8(B0 + ko);
                bN[1] = cvt8(B1 + ko);
            }
            acc[0][0] = MFMA16(aC[0], bC[0], acc[0][0]);
            acc[0][1] = MFMA16(aC[0], bC[1], acc[0][1]);
            acc[1][0] = MFMA16(aC[1], bC[0], acc[1][0]);
            acc[1][1] = MFMA16(aC[1], bC[1], acc[1][1]);
            aC[0] = aN[0]; aC[1] = aN[1]; bC[0] = bN[0]; bC[1] = bN[1];
        }

#pragma unroll
        for (int mi = 0; mi < 2; ++mi)
#pragma unroll
            for (int ni = 0; ni < 2; ++ni)
#pragma unroll
                for (int r = 0; r < 4; ++r)
                    red[w][mi * 16 + q * 4 + r][ni * 16 + r16] = acc[mi][ni][r];
        __syncthreads();

        const int m  = tid >> 3;              // 0..31
        const int n4 = (tid & 7) * 4;         // 0..28
        f32x4 s = *(const f32x4*)&red[0][m][n4];
#pragma unroll
        for (int ww = 1; ww < 4; ++ww) {
            const f32x4 v = *(const f32x4*)&red[ww][m][n4];
            s.x += v.x; s.y += v.y; s.z += v.z; s.w += v.w;
        }
        const float sc = 1.0f / 64.0f;
        ushort4 o;
        o.x = (unsigned short)f2bf(s.x * sc);
        o.y = (unsigned short)f2bf(s.y * sc);
        o.z = (unsigned short)f2bf(s.z * sc);
        o.w = (unsigned short)f2bf(s.w * sc);
        *(ushort4*)(Gsum + (size_t)b * 65536 + (size_t)(tm + m) * 256 + tn + n4) = o;
        return;
    }

    // ---- pq part ----
    const int lb0 = bid - 256;
    const bool isP = (lb0 < 64);
    const int lb = isP ? lb0 : lb0 - 64;
    const int h = lb >> 3;
    const int t = lb & 7;
    const int tm = (t >> 1) * 64;
    const int tn = (t & 1) * 128;
    const int wm = (w >> 1) * 32, wn = (w & 1) * 64;

    f32x4 acc[2][4];
#pragma unroll
    for (int mi = 0; mi < 2; ++mi)
#pragma unroll
        for (int ni = 0; ni < 4; ++ni) acc[mi][ni] = (f32x4){0.f,0.f,0.f,0.f};

#pragma unroll
    for (int kk = 0; kk < 2; ++kk) {
        const int d0 = kk * 32 + q * 8;
        bf16x8 a[2], bb[4];
        if (isP) {
#pragma unroll
            for (int mi = 0; mi < 2; ++mi) {
                const int m = tm + wm + mi * 16 + r16;
                a[mi] = cvt8(Wo + (size_t)m * HD_ + h * 64 + d0);
            }
#pragma unroll
            for (int ni = 0; ni < 4; ++ni) {
                const int n = tn + wn + ni * 16 + r16;
#pragma unroll
                for (int j = 0; j < 8; ++j)
                    bb[ni][j] = f2bf(Wv[(size_t)(h * 64 + d0 + j) * CKV_ + n]);
            }
        } else {
#pragma unroll
            for (int mi = 0; mi < 2; ++mi) {
                const int m = tm + wm + mi * 16 + r16;
#pragma unroll
                for (int j = 0; j < 8; ++j)
                    a[mi][j] = f2bf(Wq[(size_t)(h * 64 + d0 + j) * CQ_ + m]);
            }
#pragma unroll
            for (int ni = 0; ni < 4; ++ni) {
                const int n = tn + wn + ni * 16 + r16;
#pragma unroll
                for (int j = 0; j < 8; ++j)
                    bb[ni][j] = f2bf(Wk[(size_t)(h * 64 + d0 + j) * CKV_ + n]);
            }
        }
#pragma unroll
        for (int mi = 0; mi < 2; ++mi)
#pragma unroll
            for (int ni = 0; ni < 4; ++ni)
                acc[mi][ni] = MFMA16(a[mi], bb[ni], acc[mi][ni]);
    }

#pragma unroll
    for (int mi = 0; mi < 2; ++mi)
#pragma unroll
        for (int ni = 0; ni < 4; ++ni)
#pragma unroll
            for (int r = 0; r < 4; ++r) {
                const int m = tm + wm + mi * 16 + q * 4 + r;
                const int n = tn + wn + ni * 16 + r16;
                if (isP)  P [(size_t)m * 2048 + h * 256 + n] = (unsigned short)f2bf(acc[mi][ni][r]);
                else      Qt[((size_t)h * 256 + m) * 256 + n] = (unsigned short)f2bf(acc[mi][ni][r]);
            }
}

// -------------------------------------------------------------------------
// Kernel 2: zgemm.  Zt_b[cq][h*256+c'] = sum_{c''} Qt[(h,cq)][c'']*Gs_b[c'][c'']
// 64x64 tiles, grid (16,8,4)=512 blocks.  Double-buffered K-loop.
// -------------------------------------------------------------------------
__global__ __launch_bounds__(256) void zgemm_kernel(
    const unsigned short* __restrict__ Qt,
    const unsigned short* __restrict__ Gsum,
    unsigned short* __restrict__ Zt)
{
    const int t = blockIdx.x;   // 0..15
    const int h = blockIdx.y;
    const int b = blockIdx.z;
    const int tid = threadIdx.x;
    const int w = tid >> 6, L = tid & 63;
    const int r16 = L & 15, q = L >> 4;
    const int tm = (t >> 2) * 64;
    const int tn = (t & 3) * 64;
    const int wm = (w >> 1) * 32, wn = (w & 1) * 32;

    const unsigned short* Qh = Qt + (size_t)h * 65536;
    const unsigned short* Gb = Gsum + (size_t)b * 65536;
    const unsigned short* A0 = Qh + (size_t)(tm + wm + r16) * 256;
    const unsigned short* A1 = A0 + 16 * 256;
    const unsigned short* B0 = Gb + (size_t)(tn + wn + r16) * 256;
    const unsigned short* B1 = B0 + 16 * 256;
    const int k0 = q * 8;

    f32x4 acc[2][2];
#pragma unroll
    for (int mi = 0; mi < 2; ++mi)
#pragma unroll
        for (int ni = 0; ni < 2; ++ni) acc[mi][ni] = (f32x4){0.f,0.f,0.f,0.f};

    bf16x8 aC[2], bC[2];
    aC[0] = *(const bf16x8*)(A0 + k0);
    aC[1] = *(const bf16x8*)(A1 + k0);
    bC[0] = *(const bf16x8*)(B0 + k0);
    bC[1] = *(const bf16x8*)(B1 + k0);

#pragma unroll
    for (int kk = 0; kk < 8; ++kk) {
        bf16x8 aN[2], bN[2];
        if (kk < 7) {
            const int ko = k0 + (kk + 1) * 32;
            aN[0] = *(const bf16x8*)(A0 + ko);
            aN[1] = *(const bf16x8*)(A1 + ko);
            bN[0] = *(const bf16x8*)(B0 + ko);
            bN[1] = *(const bf16x8*)(B1 + ko);
        }
        acc[0][0] = MFMA16(aC[0], bC[0], acc[0][0]);
        acc[0][1] = MFMA16(aC[0], bC[1], acc[0][1]);
        acc[1][0] = MFMA16(aC[1], bC[0], acc[1][0]);
        acc[1][1] = MFMA16(aC[1], bC[1], acc[1][1]);
        aC[0] = aN[0]; aC[1] = aN[1]; bC[0] = bN[0]; bC[1] = bN[1];
    }

    unsigned short* Zb = Zt + (size_t)b * 256 * 2048;
#pragma unroll
    for (int mi = 0; mi < 2; ++mi)
#pragma unroll
        for (int ni = 0; ni < 2; ++ni)
#pragma unroll
            for (int r = 0; r < 4; ++r) {
                const int m = tm + wm + mi * 16 + q * 4 + r;       // cq
                const int n = tn + wn + ni * 16 + r16;             // c'
                Zb[(size_t)m * 2048 + h * 256 + n] = (unsigned short)f2bf(acc[mi][ni][r]);
            }
}

// -------------------------------------------------------------------------
// Kernel 3: ngemm, full-K in one block.  N[b][c][cq] = sum_k P[c][k]*Zt_b[cq][k]
// 32x32 tiles, grid (64,4)=256 blocks; wave-level split-K (4x512) + LDS reduce.
// -------------------------------------------------------------------------
__global__ __launch_bounds__(256) void ngemm_kernel(
    const unsigned short* __restrict__ P,
    const unsigned short* __restrict__ Zt,
    unsigned short* __restrict__ Nbf)
{
    const int t  = blockIdx.x;            // 0..63
    const int b  = blockIdx.y;
    const int tid = threadIdx.x;
    const int w = tid >> 6, L = tid & 63;
    const int r16 = L & 15, q = L >> 4;
    const int tm = (t >> 3) * 32;         // c
    const int tn = (t & 7) * 32;          // cq

    const unsigned short* Zb = Zt + (size_t)b * 256 * 2048;
    const unsigned short* A0 = P  + (size_t)(tm + r16) * 2048;
    const unsigned short* A1 = A0 + (size_t)16 * 2048;
    const unsigned short* B0 = Zb + (size_t)(tn + r16) * 2048;
    const unsigned short* B1 = B0 + (size_t)16 * 2048;
    const int k0 = w * 512 + q * 8;

    f32x4 acc[2][2];
#pragma unroll
    for (int mi = 0; mi < 2; ++mi)
#pragma unroll
        for (int ni = 0; ni < 2; ++ni) acc[mi][ni] = (f32x4){0.f,0.f,0.f,0.f};

    bf16x8 aC[2], bC[2];
    aC[0] = *(const bf16x8*)(A0 + k0);
    aC[1] = *(const bf16x8*)(A1 + k0);
    bC[0] = *(const bf16x8*)(B0 + k0);
    bC[1] = *(const bf16x8*)(B1 + k0);

#pragma unroll
    for (int kk = 0; kk < 16; ++kk) {
        bf16x8 aN[2], bN[2];
        if (kk < 15) {
            const int ko = k0 + (kk + 1) * 32;
            aN[0] = *(const bf16x8*)(A0 + ko);
            aN[1] = *(const bf16x8*)(A1 + ko);
            bN[0] = *(const bf16x8*)(B0 + ko);
            bN[1] = *(const bf16x8*)(B1 + ko);
        }
        acc[0][0] = MFMA16(aC[0], bC[0], acc[0][0]);
        acc[0][1] = MFMA16(aC[0], bC[1], acc[0][1]);
        acc[1][0] = MFMA16(aC[1], bC[0], acc[1][0]);
        acc[1][1] = MFMA16(aC[1], bC[1], acc[1][1]);
        aC[0] = aN[0]; aC[1] = aN[1]; bC[0] = bN[0]; bC[1] = bN[1];
    }

    __shared__ float red[4][32][36];
#pragma unroll
    for (int mi = 0; mi < 2; ++mi)
#pragma unroll
        for (int ni = 0; ni < 2; ++ni)
#pragma unroll
            for (int r = 0; r < 4; ++r)
                red[w][mi * 16 + q * 4 + r][ni * 16 + r16] = acc[mi][ni][r];
    __syncthreads();

    const int m  = tid >> 3;              // 0..31 (c)
    const int n4 = (tid & 7) * 4;         // 0..28 (cq)
    f32x4 s = *(const f32x4*)&red[0][m][n4];
#pragma unroll
    for (int ww = 1; ww < 4; ++ww) {
        const f32x4 v = *(const f32x4*)&red[ww][m][n4];
        s.x += v.x; s.y += v.y; s.z += v.z; s.w += v.w;
    }
    ushort4 o;
    o.x = (unsigned short)f2bf(s.x);
    o.y = (unsigned short)f2bf(s.y);
    o.z = (unsigned short)f2bf(s.z);
    o.w = (unsigned short)f2bf(s.w);
    *(ushort4*)(Nbf + (size_t)b * 65536 + (size_t)(tm + m) * 256 + tn + n4) = o;
}

// -------------------------------------------------------------------------
// Kernel 4: final.  out[b][c][n] = g*sum_cq Nbf[b][c][cq]*x_q[b][cq][n] + x_q[b][c][n]
// B-operand assembled DIRECTLY from f32 x_q (8 coalesced dword loads + f2bf
// per fragment) — removes the x_q transpose stage + xqt buffer entirely.
// 64x64 tiles, grid (32,4,4)=512 blocks.  Double-buffered K-loop.
// -------------------------------------------------------------------------
__global__ __launch_bounds__(256) void final_kernel(
    const unsigned short* __restrict__ Nbf,
    const float* __restrict__ x_q,
    const float* __restrict__ gamma,
    float* __restrict__ out)
{
    const int nblk = blockIdx.x * 64;
    const int cblk = blockIdx.y * 64;
    const int b    = blockIdx.z;
    const int tid  = threadIdx.x;
    const int w = tid >> 6, L = tid & 63;
    const int r16 = L & 15, q = L >> 4;
    const int wc = (w >> 1) * 32;
    const int wn = (w & 1) * 32;

    const unsigned short* Nb = Nbf + (size_t)b * 65536;
    const float* Xb = x_q + (size_t)b * CQ_ * NQ_;   // [cq][n]
    const float g = gamma[0];

    const unsigned short* A0 = Nb + (size_t)(cblk + wc + r16) * 256;
    const unsigned short* A1 = A0 + 16 * 256;
    const int n0 = nblk + wn + r16;     // B row for fragment 0
    const int n1 = n0 + 16;             // B row for fragment 1
    const int k0 = q * 8;

    f32x4 acc[2][2];
#pragma unroll
    for (int mi = 0; mi < 2; ++mi)
#pragma unroll
        for (int ni = 0; ni < 2; ++ni) acc[mi][ni] = (f32x4){0.f,0.f,0.f,0.f};

    bf16x8 aC[2], bC[2];
    aC[0] = *(const bf16x8*)(A0 + k0);
    aC[1] = *(const bf16x8*)(A1 + k0);
#pragma unroll
    for (int j = 0; j < 8; ++j) {
        bC[0][j] = f2bf(Xb[(size_t)(k0 + j) * NQ_ + n0]);
        bC[1][j] = f2bf(Xb[(size_t)(k0 + j) * NQ_ + n1]);
    }

#pragma unroll
    for (int kk = 0; kk < 8; ++kk) {
        bf16x8 aN[2], bN[2];
        if (kk < 7) {
            const int ko = k0 + (kk + 1) * 32;
            aN[0] = *(const bf16x8*)(A0 + ko);
            aN[1] = *(const bf16x8*)(A1 + ko);
#pragma unroll
            for (int j = 0; j < 8; ++j) {
                bN[0][j] = f2bf(Xb[(size_t)(ko + j) * NQ_ + n0]);
                bN[1][j] = f2bf(Xb[(size_t)(ko + j) * NQ_ + n1]);
            }
        }
        acc[0][0] = MFMA16(aC[0], bC[0], acc[0][0]);
        acc[0][1] = MFMA16(aC[0], bC[1], acc[0][1]);
        acc[1][0] = MFMA16(aC[1], bC[0], acc[1][0]);
        acc[1][1] = MFMA16(aC[1], bC[1], acc[1][1]);
        aC[0] = aN[0]; aC[1] = aN[1]; bC[0] = bN[0]; bC[1] = bN[1];
    }

#pragma unroll
    for (int mi = 0; mi < 2; ++mi)
#pragma unroll
        for (int ni = 0; ni < 2; ++ni)
#pragma unroll
            for (int r = 0; r < 4; ++r) {
                const int c = cblk + wc + mi * 16 + q * 4 + r;
                const int n = nblk + wn + ni * 16 + r16;
                const size_t idx = ((size_t)b * CQ_ + c) * NQ_ + n;
                out[idx] = g * acc[mi][ni][r] + Xb[(size_t)c * NQ_ + n];
            }
}

// -------------------------------------------------------------------------
extern "C" void kernel_launch(void* const* d_in, const int* in_sizes, int n_in,
                              void* d_out, int out_size, void* d_ws, size_t ws_size,
                              hipStream_t stream) {
    const float* x_q   = (const float*)d_in[0];
    const float* x_kv  = (const float*)d_in[1];
    const float* Wq    = (const float*)d_in[2];
    const float* Wk    = (const float*)d_in[3];
    const float* Wv    = (const float*)d_in[4];
    const float* Wo    = (const float*)d_in[5];
    const float* gamma = (const float*)d_in[6];
    float* out = (float*)d_out;

    char* ws = (char*)d_ws;
    // ws layout (bytes):
    //   Gsum bf16 [4][256][256]        0 ..   524288
    //   P    bf16 [256][2048]     524288 ..  1572864
    //   Qt   bf16 [2048][256]    1572864 ..  2621440
    //   Zt   bf16 [4][256][2048] 2621440 ..  6815744
    //   Nbf  bf16 [4][256][256]  6815744 ..  7340032
    unsigned short* Gsum = (unsigned short*)(ws);
    unsigned short* P    = (unsigned short*)(ws + 524288);
    unsigned short* Qt   = (unsigned short*)(ws + 1572864);
    unsigned short* Zt   = (unsigned short*)(ws + 2621440);
    unsigned short* Nbf  = (unsigned short*)(ws + 6815744);

    gram_pq_kernel<<<dim3(384), 256, 0, stream>>>(x_kv, Wq, Wk, Wv, Wo,
                                                  Gsum, P, Qt);
    zgemm_kernel<<<dim3(16, 8, 4), 256, 0, stream>>>(Qt, Gsum, Zt);
    ngemm_kernel<<<dim3(64, 4), 256, 0, stream>>>(P, Zt, Nbf);
    final_kernel<<<dim3(32, 4, 4), 256, 0, stream>>>(Nbf, x_q, gamma, out);
}